// Round 12
// baseline (256.593 us; speedup 1.0000x reference)
//
#include <hip/hip_runtime.h>
#include <math.h>

// Problem constants (fixed by the reference)
#define MM 12       // M
#define KK 2        // K
#define DD 512      // D
#define CIN 4096    // C_IN
#define NCLS 8
#define NV 16       // N (videos) == LSTM step count
#define TT 32       // T
// Only LSTM batch row t=31 is ever consumed (rows independent; out uses hs[:, -1, :]).

typedef unsigned long long u64;
typedef __attribute__((ext_vector_type(8))) __bf16 bf16x8;
typedef __attribute__((ext_vector_type(4))) float f32x4;

// ws float offsets (end 845952 floats = 3.23 MiB <= ws)
#define PART_F   0            // 4*192*1024 floats
#define POOLED_F 786432       // 16*512 -> ends 794624
#define TAGGX_F  794752       // 128 tags, stride-16 u32 -> ends 796800
#define HGLOB_F  796800       // 16*512 self-tagged u64 = 16384 floats (8B aligned)
#define GX_F     813184       // 32*16*64 floats = 32768 -> ends 845952
#define PART_KS_STRIDE (192 * 1024)

#define MFMA_BF16(A, B, C) __builtin_amdgcn_mfma_f32_16x16x32_bf16((A), (B), (C), 0, 0, 0)
// AGENT scope ops: release does L2 writeback on gfx950 -> proven cross-XCD handoff.
#define LOADR(p)      __hip_atomic_load((p), __ATOMIC_RELAXED, __HIP_MEMORY_SCOPE_AGENT)
#define LOADACQ(p)    __hip_atomic_load((p), __ATOMIC_ACQUIRE, __HIP_MEMORY_SCOPE_AGENT)
#define STOREREL(p, v) __hip_atomic_store((p), (v), __ATOMIC_RELEASE, __HIP_MEMORY_SCOPE_AGENT)
// SYSTEM scope: sc0+sc1 -> L3 coherence point (R4: == agent for relaxed ops).
#define LOADS(p)      __hip_atomic_load((p), __ATOMIC_RELAXED, __HIP_MEMORY_SCOPE_SYSTEM)
#define EXCHS(p, v)   (void)__hip_atomic_exchange((p), (v), __ATOMIC_RELAXED, __HIP_MEMORY_SCOPE_SYSTEM)

// sc0-only access: bypasses L1, served by the local XCD L2 — fast path when
// publisher+reader share an XCD (workers all have bid%8==0 -> same XCD).
// NOT globally coherent; always paired with a system-scope fallback.
// R10 lesson: the publish must be issued by ONE wave (16 active lanes, one
// coalesced vector op). Distributing it across 16 waves serializes same-line
// atomics at the coherence point (77 -> 159 µs regression).
static __device__ __forceinline__ u64 ld_sc0(const u64* p) {
  u64 v;
  asm volatile("global_load_dwordx2 %0, %1, off sc0\n\ts_waitcnt vmcnt(0)"
               : "=v"(v) : "v"(p) : "memory");
  return v;
}
static __device__ __forceinline__ void st_sc0(u64* p, u64 v) {
  asm volatile("global_store_dwordx2 %0, %1, off sc0" :: "v"(p), "v"(v) : "memory");
}

// f32 -> bf16 hi/lo split (truncation; lo captures the residual). Bitwise
// identical to the proven inline staging code from R0-R11.
static __device__ __forceinline__ void cvt_store(
    unsigned short* __restrict__ hb, unsigned short* __restrict__ lb,
    int idx, float4 v) {
  unsigned ux = __float_as_uint(v.x), uy = __float_as_uint(v.y);
  unsigned uz = __float_as_uint(v.z), uw = __float_as_uint(v.w);
  *(uint2*)&hb[idx] = make_uint2((ux >> 16) | (uy & 0xFFFF0000u),
                                 (uz >> 16) | (uw & 0xFFFF0000u));
  unsigned lx = __float_as_uint(v.x - __uint_as_float(ux & 0xFFFF0000u));
  unsigned ly = __float_as_uint(v.y - __uint_as_float(uy & 0xFFFF0000u));
  unsigned lz = __float_as_uint(v.z - __uint_as_float(uz & 0xFFFF0000u));
  unsigned lw = __float_as_uint(v.w - __uint_as_float(uw & 0xFFFF0000u));
  *(uint2*)&lb[idx] = make_uint2((lx >> 16) | (ly & 0xFFFF0000u),
                                 (lz >> 16) | (lw & 0xFFFF0000u));
}

// ============================================================================
// Kernel 1: barrier-free single-wave GEMM, 2-deep prefetch. 1024 WGs x 64 thr.
// (R11-verified, byte-identical.) wg -> ks = wg&3, ot = (wg>>2)&63, jq = (wg>>8)&3.
// ============================================================================
__global__ __launch_bounds__(64, 1) void k_gemm(
    const float* __restrict__ base_out, const float* __restrict__ w_a,
    float* __restrict__ part)
{
  const int wg = blockIdx.x;          // 0..1023
  const int ks = wg & 3;
  const int ot = (wg >> 2) & 63;
  const int jq = (wg >> 8) & 3;
  const int cc0 = ks * 1024;
  const int lane = threadIdx.x;       // 0..63

  __shared__ __align__(16) unsigned short Ah[16 * 40], Al[16 * 40];
  __shared__ __align__(16) unsigned short Bh[48 * 40], Bl[48 * 40];

  const int sq = lane & 7;            // cc float4 quad (0..7)
  const int sr = lane >> 3;           // staging row (0..7)

  unsigned boff[6];
#pragma unroll
  for (int rep = 0; rep < 6; ++rep) {
    const int jl = sr + 8 * rep;      // 0..47
    const int j = jq * 48 + jl;       // 0..191
    const int n = j / 12, m = j - n * 12;
    boff[rep] = (unsigned)(((n * TT + 31) * MM + m) * CIN + cc0 + sq * 4);
  }
  unsigned aoff[2];
#pragma unroll
  for (int repA = 0; repA < 2; ++repA)
    aoff[repA] = (unsigned)((ot * 16 + sr + 8 * repA) * CIN + cc0 + sq * 4);

  f32x4 acc0 = {0.f, 0.f, 0.f, 0.f}, acc1 = acc0, acc2 = acc0;

  float4 pa0[2], pb0[6], pa1[2], pb1[6];
  // preload step 0 into set0 (base offsets), step 1 into set1 (+32)
#pragma unroll
  for (int repA = 0; repA < 2; ++repA) pa0[repA] = *(const float4*)&w_a[aoff[repA]];
#pragma unroll
  for (int rep = 0; rep < 6; ++rep) pb0[rep] = *(const float4*)&base_out[boff[rep]];
#pragma unroll
  for (int repA = 0; repA < 2; ++repA) {
    aoff[repA] += 32; pa1[repA] = *(const float4*)&w_a[aoff[repA]];
  }
#pragma unroll
  for (int rep = 0; rep < 6; ++rep) {
    boff[rep] += 32; pb1[rep] = *(const float4*)&base_out[boff[rep]];
  }

#define STAGE_SET(PA, PB)                                                   \
  {                                                                         \
    _Pragma("unroll")                                                       \
    for (int repA = 0; repA < 2; ++repA)                                    \
      cvt_store(Ah, Al, (sr + 8 * repA) * 40 + sq * 4, PA[repA]);           \
    _Pragma("unroll")                                                       \
    for (int rep = 0; rep < 6; ++rep)                                       \
      cvt_store(Bh, Bl, (sr + 8 * rep) * 40 + sq * 4, PB[rep]);             \
  }
#define LOAD_SET(PA, PB)                                                    \
  {                                                                         \
    _Pragma("unroll")                                                       \
    for (int repA = 0; repA < 2; ++repA) {                                  \
      aoff[repA] += 32; PA[repA] = *(const float4*)&w_a[aoff[repA]];        \
    }                                                                       \
    _Pragma("unroll")                                                       \
    for (int rep = 0; rep < 6; ++rep) {                                     \
      boff[rep] += 32; PB[rep] = *(const float4*)&base_out[boff[rep]];      \
    }                                                                       \
  }
#define MFMA_STEP()                                                         \
  {                                                                         \
    const int koff = (lane >> 4) * 8;                                       \
    const int fra = (lane & 15) * 40 + koff;                                \
    bf16x8 oh = *(const bf16x8*)&Ah[fra];                                   \
    bf16x8 ol = *(const bf16x8*)&Al[fra];                                   \
    {                                                                       \
      const int r0 = (0 * 16 + (lane & 15)) * 40 + koff;                    \
      bf16x8 jh = *(const bf16x8*)&Bh[r0], jl = *(const bf16x8*)&Bl[r0];    \
      acc0 = MFMA_BF16(jh, oh, acc0);                                       \
      acc0 = MFMA_BF16(jh, ol, acc0);                                       \
      acc0 = MFMA_BF16(jl, oh, acc0);                                       \
    }                                                                       \
    {                                                                       \
      const int r1 = (1 * 16 + (lane & 15)) * 40 + koff;                    \
      bf16x8 jh = *(const bf16x8*)&Bh[r1], jl = *(const bf16x8*)&Bl[r1];    \
      acc1 = MFMA_BF16(jh, oh, acc1);                                       \
      acc1 = MFMA_BF16(jh, ol, acc1);                                       \
      acc1 = MFMA_BF16(jl, oh, acc1);                                       \
    }                                                                       \
    {                                                                       \
      const int r2 = (2 * 16 + (lane & 15)) * 40 + koff;                    \
      bf16x8 jh = *(const bf16x8*)&Bh[r2], jl = *(const bf16x8*)&Bl[r2];    \
      acc2 = MFMA_BF16(jh, oh, acc2);                                       \
      acc2 = MFMA_BF16(jh, ol, acc2);                                       \
      acc2 = MFMA_BF16(jl, oh, acc2);                                       \
    }                                                                       \
  }

  for (int st = 0; st < 32; st += 2) {
    // even step: consume set0; issue loads for st+2 into set0
    STAGE_SET(pa0, pb0);
    if (st + 2 < 32) LOAD_SET(pa0, pb0);
    MFMA_STEP();
    // odd step: consume set1; issue loads for st+3 into set1
    STAGE_SET(pa1, pb1);
    if (st + 3 < 32) LOAD_SET(pa1, pb1);
    MFMA_STEP();
  }
#undef STAGE_SET
#undef LOAD_SET
#undef MFMA_STEP

  // C/D layout: col(o) = lane&15, row(j) = (lane>>4)*4 + reg   [m89-verified]
  const int o = ot * 16 + (lane & 15);
  const int jr = (lane >> 4) * 4;
#pragma unroll
  for (int r = 0; r < 4; ++r) {
    part[((size_t)ks * 192 + jq * 48 + 0 * 16 + jr + r) * 1024 + o] = acc0[r];
    part[((size_t)ks * 192 + jq * 48 + 1 * 16 + jr + r) * 1024 + o] = acc1[r];
    part[((size_t)ks * 192 + jq * 48 + 2 * 16 + jr + r) * 1024 + o] = acc2[r];
  }
  // part visibility to k_pool via the stream/kernel boundary (no fence).
}

// ============================================================================
// Kernel 2: pool (phase B) standalone. 256 WGs x 256 threads. (unchanged)
// ============================================================================
__global__ __launch_bounds__(256, 1) void k_pool(
    const float* __restrict__ dist, const float* __restrict__ part,
    float* __restrict__ pooled)
{
  const int wg = blockIdx.x;   // 0..255
  const int tid = threadIdx.x; // 0..255

  __shared__ float Asum_s[KK * MM * MM];

  const int n = wg >> 4, cb = (wg & 15) * 32;
  const unsigned dbase = (unsigned)((n * TT + 31) * (3 * KK * MM * MM));
  for (int f = tid; f < KK * MM * MM; f += 256)
    Asum_s[f] = dist[dbase + f] + dist[dbase + KK * MM * MM + f]
              + dist[dbase + 2 * KK * MM * MM + f];
  __syncthreads();
  if (tid < 32) {
    const int c = cb + tid;
    float nd[KK][MM];
#pragma unroll
    for (int k = 0; k < KK; ++k)
#pragma unroll
      for (int v = 0; v < MM; ++v) {
        const size_t off = (size_t)(n * MM + v) * 1024 + k * DD + c;
        nd[k][v] = part[off] + part[off + PART_KS_STRIDE]
                 + part[off + 2 * PART_KS_STRIDE] + part[off + 3 * PART_KS_STRIDE];
      }
    float accm = 0.f;
#pragma unroll
    for (int w = 0; w < MM; ++w) {
      float sw = 0.f;
#pragma unroll
      for (int k = 0; k < KK; ++k)
#pragma unroll
        for (int v = 0; v < MM; ++v) sw += nd[k][v] * Asum_s[(k * MM + v) * MM + w];
      accm += fmaxf(sw, 0.f);
    }
    pooled[n * DD + c] = accm * (1.f / 12.f);
  }
  // pooled visibility to k_rest via the stream/kernel boundary.
}

// ============================================================================
// Kernel 3: gx + LSTM + classifier.  256 WGs x 1024 threads.
// R12 head changes (loop body byte-identical to R11):
//  - producers: all 1024 threads (4-way quarter-dots + LDS reduce) -> ~4x
//    fewer serialized HBM-latency batches on the critical-path head.
//  - workers: whh loads issued into registers BEFORE the gx wait; h(s=0)
//    (= gates from gx + 0.0 dot, bitwise-identical to old s=0 path)
//    published BEFORE whh LDS writes; loop runs s=1..15.
// ============================================================================
__global__ __launch_bounds__(1024, 1) void k_rest(
    const float* __restrict__ pooled,
    const float* __restrict__ w_ih, const float* __restrict__ w_hh,
    const float* __restrict__ b_ih, const float* __restrict__ b_hh,
    const float* __restrict__ w_cls, const float* __restrict__ b_cls,
    unsigned* __restrict__ tagGX, float* __restrict__ gxg,
    u64* __restrict__ hg64, float* __restrict__ out)
{
  const int wg = blockIdx.x;    // 0..255
  const int tid = threadIdx.x;  // 0..1023

  __shared__ __align__(16) float whh_s[64][516];  // 132 KB; reused as h-history in classifier
  __shared__ float gx_s[16][64];                  // [step][local gate row]
  __shared__ __align__(16) float h_s[DD];
  __shared__ float dot_s[64];
  __shared__ float gxp_s[1024];                   // producer partials

  if ((wg & 7) != 0) {
    // ---- gx producer: gate rows gr = dd*16 + j, dd = m + 32*(k-1) ----
    const int k = wg & 7;
    if (k > 4) return;                 // 96 WGs exit immediately
    const int m = wg >> 3;             // 0..31 (serves worker w = m)
    const int dd = m + 32 * (k - 1);   // 0..127
    {
      const int q4 = tid >> 8;         // quarter 0..3
      const int r = tid & 255;
      const int n = r & 15, j = r >> 4;
      const int gr = dd * 16 + j;      // global gate row (g = k-1, dim = 16m+j)
      const float4* wr = (const float4*)&w_ih[(size_t)gr * DD];
      const float4* pv = (const float4*)&pooled[(size_t)n * DD];
      float a = 0.f;
#pragma unroll 8
      for (int q = q4 * 32; q < q4 * 32 + 32; ++q) {
        float4 x = wr[q], y = pv[q];
        a += x.x * y.x + x.y * y.y + x.z * y.z + x.w * y.w;
      }
      gxp_s[tid] = a;
    }
    __syncthreads();
    if (tid < 256) {
      const int n = tid & 15, j = tid >> 4;
      const int gr = dd * 16 + j;
      const float a = ((gxp_s[tid] + gxp_s[tid + 256]) + gxp_s[tid + 512])
                    + gxp_s[tid + 768] + b_ih[gr] + b_hh[gr];
      // k2-native layout: gxg[w][n][rl], rl = (k-1)*16 + j
      gxg[m * 1024 + n * 64 + (k - 1) * 16 + j] = a;
    }
    __syncthreads();   // drains vmcnt -> gx stores complete before release
    if (tid == 0) STOREREL(&tagGX[dd * 16], 1u);   // release: wbL2 -> L3
    return;
  }

  // ============================ LSTM worker =================================
  const int w = wg >> 3;   // 0..31; owns h-dims [w*16, w*16+16)
  float c_reg = 0.f;       // gate wave (tid<16) LSTM cell state

  // ---- issue whh loads into registers (in flight during the gx wait) ----
  float4 wtmp[8];
#pragma unroll
  for (int it = 0; it < 8; ++it) {
    const int f = tid + it * 1024;
    const int rr = f >> 7, c4 = (f & 127) * 4;
    const int grow = (rr >> 4) * DD + w * 16 + (rr & 15);
    wtmp[it] = *(const float4*)&w_hh[(size_t)grow * DD + c4];
  }
  // ---- wait for this worker's 4 gx tiles (k=1..4) ----
  if (tid < 64) {
    bool done;
    do {
      int t0 = (int)LOADR(&tagGX[(w + 32 * (tid & 3)) * 16]);
      done = __all(t0 == 1);           // 0xAA poison != 1
    } while (!done);
  }
  __syncthreads();
  // gx gather: system loads (bypass caches; producer released to L3)
  gx_s[tid >> 6][tid & 63] =
      __uint_as_float(LOADS((const unsigned*)&gxg[w * 1024 + tid]));
  __syncthreads();

  // ---- step 0: h depends only on gx (recurrent dot == +0.0 exactly) ----
  if (tid < 16) {
    const float pi = gx_s[0][tid]      + 0.0f;
    const float pf = gx_s[0][16 + tid] + 0.0f;
    const float pg = gx_s[0][32 + tid] + 0.0f;
    const float po = gx_s[0][48 + tid] + 0.0f;
    const float si = 1.f / (1.f + expf(-pi));
    const float sf = 1.f / (1.f + expf(-pf));
    const float so = 1.f / (1.f + expf(-po));
    c_reg = sf * c_reg + si * tanhf(pg);
    const float hn = so * tanhf(c_reg);
    const u64 pk = ((u64)__float_as_uint(hn) << 32) | (u64)1u;
    u64* pp = &hg64[w * 16 + tid];     // s = 0
    st_sc0(pp, pk);    // fast visibility within this XCD's L2 (one wave, coalesced)
    EXCHS(pp, pk);     // durable publish at the device coherence point
  }

  // ---- write staged whh to LDS (loads already landed / land now) ----
#pragma unroll
  for (int it = 0; it < 8; ++it) {
    const int f = tid + it * 1024;
    const int rr = f >> 7, c4 = (f & 127) * 4;
    *(float4*)&whh_s[rr][c4] = wtmp[it];
  }
  __syncthreads();

  // ---- LSTM loop: steps 1..15; hybrid sc0/system data-spin all-gather ----
  {
    const int r = tid >> 4;    // local gate row 0..63
    const int lj = tid & 15;   // slice lane

    for (int s = 1; s < NV; ++s) {
      if (tid < DD) {
        const u64* p = &hg64[(size_t)(s - 1) * DD + tid];
        u64 v = ld_sc0(p);                       // fast path: local-XCD L2
        while ((unsigned)v != (unsigned)s) {
          v = LOADS(p);                          // fallback: L3 (guarantees progress)
          if ((unsigned)v == (unsigned)s) break;
          v = ld_sc0(p);
        }
        h_s[tid] = __uint_as_float((unsigned)(v >> 32));
      }
      __syncthreads();

      float p = 0.f;
      const float4* wrow = (const float4*)&whh_s[r][0];
      const float4* hv4 = (const float4*)h_s;
#pragma unroll
      for (int q = 0; q < 8; ++q) {
        float4 wv = wrow[lj + 16 * q];
        float4 hv = hv4[lj + 16 * q];
        p += wv.x * hv.x + wv.y * hv.y + wv.z * hv.z + wv.w * hv.w;
      }
#pragma unroll
      for (int off = 8; off; off >>= 1) p += __shfl_down(p, off, 16);
      if (lj == 0) dot_s[r] = p;
      __syncthreads();

      if (tid < 16) {
        const float pi = gx_s[s][tid]      + dot_s[tid];
        const float pf = gx_s[s][16 + tid] + dot_s[16 + tid];
        const float pg = gx_s[s][32 + tid] + dot_s[32 + tid];
        const float po = gx_s[s][48 + tid] + dot_s[48 + tid];
        const float si = 1.f / (1.f + expf(-pi));
        const float sf = 1.f / (1.f + expf(-pf));
        const float so = 1.f / (1.f + expf(-po));
        c_reg = sf * c_reg + si * tanhf(pg);
        const float hn = so * tanhf(c_reg);
        const u64 pk = ((u64)__float_as_uint(hn) << 32) | (u64)(unsigned)(s + 1);
        u64* pp = &hg64[(size_t)s * DD + w * 16 + tid];
        st_sc0(pp, pk);    // fast visibility within this XCD's L2 (one wave, coalesced)
        EXCHS(pp, pk);     // durable publish at the device coherence point
      }
      // h_s/dot_s only rewritten after next step's barriers (two barriers away)
    }
  }

  // ---- classifier tail (worker 0 = blockIdx 0) ----
  if (wg == 0) {
    float* scratch = &whh_s[0][0];   // rows stride 516 (whh dead now)
    if (tid < DD) {
      u64 vv[NV];
#pragma unroll
      for (int n = 0; n < NV; ++n) vv[n] = LOADS(&hg64[(size_t)n * DD + tid]);
#pragma unroll
      for (int n = 0; n < NV; ++n) {
        u64 v = vv[n];
        while ((unsigned)v != (unsigned)(n + 1))
          v = LOADS(&hg64[(size_t)n * DD + tid]);   // backstop
        scratch[n * 516 + tid] = __uint_as_float((unsigned)(v >> 32));
      }
    }
    __syncthreads();
    if (tid < NV * NCLS) {
      const int n = tid >> 3, cl = tid & 7;
      const float4* hv = (const float4*)&scratch[n * 516];
      const float4* wv = (const float4*)(w_cls + (size_t)cl * DD);
      float a = b_cls[cl];
#pragma unroll 8
      for (int q = 0; q < DD / 4; ++q) {
        float4 x = hv[q], y = wv[q];
        a += x.x * y.x + x.y * y.y + x.z * y.z + x.w * y.w;
      }
      out[tid] = a;
    }
  }
}

extern "C" void kernel_launch(void* const* d_in, const int* in_sizes, int n_in,
                              void* d_out, int out_size, void* d_ws, size_t ws_size,
                              hipStream_t stream) {
  const float* base_out = (const float*)d_in[0];
  const float* dist     = (const float*)d_in[1];
  const float* w_a      = (const float*)d_in[2];
  const float* w_ih     = (const float*)d_in[3];
  const float* w_hh     = (const float*)d_in[4];
  const float* b_ih     = (const float*)d_in[5];
  const float* b_hh     = (const float*)d_in[6];
  const float* w_cls    = (const float*)d_in[7];
  const float* b_cls    = (const float*)d_in[8];
  float* out = (float*)d_out;

  float* ws = (float*)d_ws;
  float* part   = ws + PART_F;
  float* pooled = ws + POOLED_F;
  unsigned* tagGX = (unsigned*)(ws + TAGGX_F);
  u64* hg64 = (u64*)(ws + HGLOB_F);
  float* gxg = ws + GX_F;

  // Tags/values self-validate against the 0xAA re-poison (poison low word
  // 0xAAAAAAAA never equals a live tag 1..16 / 1).
  // Stream boundaries provide part -> k_pool and pooled -> k_rest visibility.
  k_gemm<<<dim3(1024), 64, 0, stream>>>(base_out, w_a, part);
  k_pool<<<dim3(256), 256, 0, stream>>>(dist, part, pooled);
  k_rest<<<dim3(256), 1024, 0, stream>>>(pooled, w_ih, w_hh, b_ih, b_hh,
                                         w_cls, b_cls, tagGX, gxg, hg64, out);
}

// Round 13
// 248.202 us; speedup vs baseline: 1.0338x; 1.0338x over previous
//
#include <hip/hip_runtime.h>
#include <math.h>

// Problem constants (fixed by the reference)
#define MM 12       // M
#define KK 2        // K
#define DD 512      // D
#define CIN 4096    // C_IN
#define NCLS 8
#define NV 16       // N (videos) == LSTM step count
#define TT 32       // T
// Only LSTM batch row t=31 is ever consumed (rows independent; out uses hs[:, -1, :]).

typedef unsigned long long u64;
typedef __attribute__((ext_vector_type(8))) __bf16 bf16x8;
typedef __attribute__((ext_vector_type(4))) float f32x4;

// ws float offsets (end 845952 floats = 3.23 MiB <= ws)
#define PART_F   0            // 4*192*1024 floats
#define POOLED_F 786432       // 16*512 -> ends 794624
#define TAGGX_F  794752       // 128 tags, stride-16 u32 -> ends 796800
#define HGLOB_F  796800       // 16*512 self-tagged u64 = 16384 floats (8B aligned)
#define GX_F     813184       // 32*16*64 floats = 32768 -> ends 845952
#define PART_KS_STRIDE (192 * 1024)

#define MFMA_BF16(A, B, C) __builtin_amdgcn_mfma_f32_16x16x32_bf16((A), (B), (C), 0, 0, 0)
// AGENT scope ops: release does L2 writeback on gfx950 -> proven cross-XCD handoff.
#define LOADR(p)      __hip_atomic_load((p), __ATOMIC_RELAXED, __HIP_MEMORY_SCOPE_AGENT)
#define LOADACQ(p)    __hip_atomic_load((p), __ATOMIC_ACQUIRE, __HIP_MEMORY_SCOPE_AGENT)
#define STOREREL(p, v) __hip_atomic_store((p), (v), __ATOMIC_RELEASE, __HIP_MEMORY_SCOPE_AGENT)
// SYSTEM scope: sc0+sc1 -> L3 coherence point (R4: == agent for relaxed ops).
#define LOADS(p)      __hip_atomic_load((p), __ATOMIC_RELAXED, __HIP_MEMORY_SCOPE_SYSTEM)
#define EXCHS(p, v)   (void)__hip_atomic_exchange((p), (v), __ATOMIC_RELAXED, __HIP_MEMORY_SCOPE_SYSTEM)

// sc0-only access: bypasses L1, served by the local XCD L2 — fast path when
// publisher+reader share an XCD (workers all have bid%8==0 -> same XCD).
// NOT globally coherent; always paired with a system-scope fallback.
// R10 lesson: the publish must be issued by ONE wave (16 active lanes, one
// coalesced vector op) — scattering it across waves serializes same-line
// atomics at the coherence point (77 -> 159 µs regression).
// R12 lesson: register staging across a spin loop gets spilled to scratch
// (VGPR_Count stayed 52, WRITE_SIZE 0.33->4.4 MB) — stage to LDS directly.
static __device__ __forceinline__ u64 ld_sc0(const u64* p) {
  u64 v;
  asm volatile("global_load_dwordx2 %0, %1, off sc0\n\ts_waitcnt vmcnt(0)"
               : "=v"(v) : "v"(p) : "memory");
  return v;
}
static __device__ __forceinline__ void st_sc0(u64* p, u64 v) {
  asm volatile("global_store_dwordx2 %0, %1, off sc0" :: "v"(p), "v"(v) : "memory");
}

// f32 -> bf16 hi/lo split (truncation; lo captures the residual). Bitwise
// identical to the proven inline staging code from R0-R12.
static __device__ __forceinline__ void cvt_store(
    unsigned short* __restrict__ hb, unsigned short* __restrict__ lb,
    int idx, float4 v) {
  unsigned ux = __float_as_uint(v.x), uy = __float_as_uint(v.y);
  unsigned uz = __float_as_uint(v.z), uw = __float_as_uint(v.w);
  *(uint2*)&hb[idx] = make_uint2((ux >> 16) | (uy & 0xFFFF0000u),
                                 (uz >> 16) | (uw & 0xFFFF0000u));
  unsigned lx = __float_as_uint(v.x - __uint_as_float(ux & 0xFFFF0000u));
  unsigned ly = __float_as_uint(v.y - __uint_as_float(uy & 0xFFFF0000u));
  unsigned lz = __float_as_uint(v.z - __uint_as_float(uz & 0xFFFF0000u));
  unsigned lw = __float_as_uint(v.w - __uint_as_float(uw & 0xFFFF0000u));
  *(uint2*)&lb[idx] = make_uint2((lx >> 16) | (ly & 0xFFFF0000u),
                                 (lz >> 16) | (lw & 0xFFFF0000u));
}

// ============================================================================
// Kernel 1: barrier-free single-wave GEMM. R13: 16o x 16j tiles, 3072 WGs x
// 64 thr -> 12 WGs/CU = 3 waves/SIMD: hardware TLP hides the load latency the
// 1-wave/SIMD R11 design exposed (~28 µs vs ~10 µs floor).
// wg -> ks = wg&3, ot = (wg>>2)&63, jq = wg>>8 (0..11).
// Per-element math bitwise-identical: same 3-MFMA chain over same K order.
// 2-deep prefetch retained. No __syncthreads (same-wave LDS ordering).
// ============================================================================
__global__ __launch_bounds__(64, 1) void k_gemm(
    const float* __restrict__ base_out, const float* __restrict__ w_a,
    float* __restrict__ part)
{
  const int wg = blockIdx.x;          // 0..3071
  const int ks = wg & 3;
  const int ot = (wg >> 2) & 63;
  const int jq = wg >> 8;             // 0..11
  const int cc0 = ks * 1024;
  const int lane = threadIdx.x;       // 0..63

  __shared__ __align__(16) unsigned short Ah[16 * 40], Al[16 * 40];
  __shared__ __align__(16) unsigned short Bh[16 * 40], Bl[16 * 40];

  const int sq = lane & 7;            // cc float4 quad (0..7)
  const int sr = lane >> 3;           // staging row (0..7)

  unsigned boff[2];
#pragma unroll
  for (int rep = 0; rep < 2; ++rep) {
    const int j = jq * 16 + sr + 8 * rep;   // 0..191
    const int n = j / 12, m = j - n * 12;
    boff[rep] = (unsigned)(((n * TT + 31) * MM + m) * CIN + cc0 + sq * 4);
  }
  unsigned aoff[2];
#pragma unroll
  for (int repA = 0; repA < 2; ++repA)
    aoff[repA] = (unsigned)((ot * 16 + sr + 8 * repA) * CIN + cc0 + sq * 4);

  f32x4 acc0 = {0.f, 0.f, 0.f, 0.f};

  float4 pa0[2], pb0[2], pa1[2], pb1[2];
  // preload step 0 into set0 (base offsets), step 1 into set1 (+32)
#pragma unroll
  for (int r2 = 0; r2 < 2; ++r2) pa0[r2] = *(const float4*)&w_a[aoff[r2]];
#pragma unroll
  for (int r2 = 0; r2 < 2; ++r2) pb0[r2] = *(const float4*)&base_out[boff[r2]];
#pragma unroll
  for (int r2 = 0; r2 < 2; ++r2) {
    aoff[r2] += 32; pa1[r2] = *(const float4*)&w_a[aoff[r2]];
  }
#pragma unroll
  for (int r2 = 0; r2 < 2; ++r2) {
    boff[r2] += 32; pb1[r2] = *(const float4*)&base_out[boff[r2]];
  }

#define STAGE_SET(PA, PB)                                                   \
  {                                                                         \
    _Pragma("unroll")                                                       \
    for (int r2 = 0; r2 < 2; ++r2)                                          \
      cvt_store(Ah, Al, (sr + 8 * r2) * 40 + sq * 4, PA[r2]);               \
    _Pragma("unroll")                                                       \
    for (int r2 = 0; r2 < 2; ++r2)                                          \
      cvt_store(Bh, Bl, (sr + 8 * r2) * 40 + sq * 4, PB[r2]);               \
  }
#define LOAD_SET(PA, PB)                                                    \
  {                                                                         \
    _Pragma("unroll")                                                       \
    for (int r2 = 0; r2 < 2; ++r2) {                                        \
      aoff[r2] += 32; PA[r2] = *(const float4*)&w_a[aoff[r2]];              \
    }                                                                       \
    _Pragma("unroll")                                                       \
    for (int r2 = 0; r2 < 2; ++r2) {                                        \
      boff[r2] += 32; PB[r2] = *(const float4*)&base_out[boff[r2]];         \
    }                                                                       \
  }
#define MFMA_STEP()                                                         \
  {                                                                         \
    const int koff = (lane >> 4) * 8;                                       \
    const int fra = (lane & 15) * 40 + koff;                                \
    bf16x8 oh = *(const bf16x8*)&Ah[fra];                                   \
    bf16x8 ol = *(const bf16x8*)&Al[fra];                                   \
    bf16x8 jh = *(const bf16x8*)&Bh[fra];                                   \
    bf16x8 jl = *(const bf16x8*)&Bl[fra];                                   \
    acc0 = MFMA_BF16(jh, oh, acc0);                                         \
    acc0 = MFMA_BF16(jh, ol, acc0);                                         \
    acc0 = MFMA_BF16(jl, oh, acc0);                                         \
  }

  for (int st = 0; st < 32; st += 2) {
    // even step: consume set0; issue loads for st+2 into set0
    STAGE_SET(pa0, pb0);
    if (st + 2 < 32) LOAD_SET(pa0, pb0);
    MFMA_STEP();
    // odd step: consume set1; issue loads for st+3 into set1
    STAGE_SET(pa1, pb1);
    if (st + 3 < 32) LOAD_SET(pa1, pb1);
    MFMA_STEP();
  }
#undef STAGE_SET
#undef LOAD_SET
#undef MFMA_STEP

  // C/D layout: col(o) = lane&15, row(j) = (lane>>4)*4 + reg   [m89-verified]
  const int o = ot * 16 + (lane & 15);
  const int jr = (lane >> 4) * 4;
#pragma unroll
  for (int r = 0; r < 4; ++r)
    part[((size_t)ks * 192 + jq * 16 + jr + r) * 1024 + o] = acc0[r];
  // part visibility to k_pool via the stream/kernel boundary (no fence).
}

// ============================================================================
// Kernel 2: pool (phase B) standalone. 256 WGs x 256 threads. (unchanged)
// ============================================================================
__global__ __launch_bounds__(256, 1) void k_pool(
    const float* __restrict__ dist, const float* __restrict__ part,
    float* __restrict__ pooled)
{
  const int wg = blockIdx.x;   // 0..255
  const int tid = threadIdx.x; // 0..255

  __shared__ float Asum_s[KK * MM * MM];

  const int n = wg >> 4, cb = (wg & 15) * 32;
  const unsigned dbase = (unsigned)((n * TT + 31) * (3 * KK * MM * MM));
  for (int f = tid; f < KK * MM * MM; f += 256)
    Asum_s[f] = dist[dbase + f] + dist[dbase + KK * MM * MM + f]
              + dist[dbase + 2 * KK * MM * MM + f];
  __syncthreads();
  if (tid < 32) {
    const int c = cb + tid;
    float nd[KK][MM];
#pragma unroll
    for (int k = 0; k < KK; ++k)
#pragma unroll
      for (int v = 0; v < MM; ++v) {
        const size_t off = (size_t)(n * MM + v) * 1024 + k * DD + c;
        nd[k][v] = part[off] + part[off + PART_KS_STRIDE]
                 + part[off + 2 * PART_KS_STRIDE] + part[off + 3 * PART_KS_STRIDE];
      }
    float accm = 0.f;
#pragma unroll
    for (int w = 0; w < MM; ++w) {
      float sw = 0.f;
#pragma unroll
      for (int k = 0; k < KK; ++k)
#pragma unroll
        for (int v = 0; v < MM; ++v) sw += nd[k][v] * Asum_s[(k * MM + v) * MM + w];
      accm += fmaxf(sw, 0.f);
    }
    pooled[n * DD + c] = accm * (1.f / 12.f);
  }
  // pooled visibility to k_rest via the stream/kernel boundary.
}

// ============================================================================
// Kernel 3: gx + LSTM + classifier.  256 WGs x 1024 threads.
// R13 = R12 minus the scratch-spill: whh staged DIRECTLY to LDS (R11-proven
// loop) before the gx wait; producer quarter-dot and early-h0 publish kept.
// ============================================================================
__global__ __launch_bounds__(1024, 1) void k_rest(
    const float* __restrict__ pooled,
    const float* __restrict__ w_ih, const float* __restrict__ w_hh,
    const float* __restrict__ b_ih, const float* __restrict__ b_hh,
    const float* __restrict__ w_cls, const float* __restrict__ b_cls,
    unsigned* __restrict__ tagGX, float* __restrict__ gxg,
    u64* __restrict__ hg64, float* __restrict__ out)
{
  const int wg = blockIdx.x;    // 0..255
  const int tid = threadIdx.x;  // 0..1023

  __shared__ __align__(16) float whh_s[64][516];  // 132 KB; reused as h-history in classifier
  __shared__ float gx_s[16][64];                  // [step][local gate row]
  __shared__ __align__(16) float h_s[DD];
  __shared__ float dot_s[64];
  __shared__ float gxp_s[1024];                   // producer partials

  if ((wg & 7) != 0) {
    // ---- gx producer: gate rows gr = dd*16 + j, dd = m + 32*(k-1) ----
    const int k = wg & 7;
    if (k > 4) return;                 // 96 WGs exit immediately
    const int m = wg >> 3;             // 0..31 (serves worker w = m)
    const int dd = m + 32 * (k - 1);   // 0..127
    {
      const int q4 = tid >> 8;         // quarter 0..3
      const int r = tid & 255;
      const int n = r & 15, j = r >> 4;
      const int gr = dd * 16 + j;      // global gate row (g = k-1, dim = 16m+j)
      const float4* wr = (const float4*)&w_ih[(size_t)gr * DD];
      const float4* pv = (const float4*)&pooled[(size_t)n * DD];
      float a = 0.f;
#pragma unroll 8
      for (int q = q4 * 32; q < q4 * 32 + 32; ++q) {
        float4 x = wr[q], y = pv[q];
        a += x.x * y.x + x.y * y.y + x.z * y.z + x.w * y.w;
      }
      gxp_s[tid] = a;
    }
    __syncthreads();
    if (tid < 256) {
      const int n = tid & 15, j = tid >> 4;
      const int gr = dd * 16 + j;
      const float a = ((gxp_s[tid] + gxp_s[tid + 256]) + gxp_s[tid + 512])
                    + gxp_s[tid + 768] + b_ih[gr] + b_hh[gr];
      // k2-native layout: gxg[w][n][rl], rl = (k-1)*16 + j
      gxg[m * 1024 + n * 64 + (k - 1) * 16 + j] = a;
    }
    __syncthreads();   // drains vmcnt -> gx stores complete before release
    if (tid == 0) STOREREL(&tagGX[dd * 16], 1u);   // release: wbL2 -> L3
    return;
  }

  // ============================ LSTM worker =================================
  const int w = wg >> 3;   // 0..31; owns h-dims [w*16, w*16+16)
  float c_reg = 0.f;       // gate wave (tid<16) LSTM cell state

  // ---- stage whh rows (64 x 512 = 128 KB) directly to LDS (R11-proven) ----
  for (int f = tid; f < 64 * 128; f += 1024) {
    const int rr = f >> 7, c4 = (f & 127) * 4;
    const int grow = (rr >> 4) * DD + w * 16 + (rr & 15);
    *(float4*)&whh_s[rr][c4] = *(const float4*)&w_hh[(size_t)grow * DD + c4];
  }
  // ---- wait for this worker's 4 gx tiles (k=1..4) ----
  if (tid < 64) {
    bool done;
    do {
      int t0 = (int)LOADR(&tagGX[(w + 32 * (tid & 3)) * 16]);
      done = __all(t0 == 1);           // 0xAA poison != 1
    } while (!done);
  }
  __syncthreads();
  // gx gather: system loads (bypass caches; producer released to L3)
  gx_s[tid >> 6][tid & 63] =
      __uint_as_float(LOADS((const unsigned*)&gxg[w * 1024 + tid]));
  __syncthreads();

  // ---- step 0: h depends only on gx (recurrent dot == +0.0 exactly) ----
  if (tid < 16) {
    const float pi = gx_s[0][tid]      + 0.0f;
    const float pf = gx_s[0][16 + tid] + 0.0f;
    const float pg = gx_s[0][32 + tid] + 0.0f;
    const float po = gx_s[0][48 + tid] + 0.0f;
    const float si = 1.f / (1.f + expf(-pi));
    const float sf = 1.f / (1.f + expf(-pf));
    const float so = 1.f / (1.f + expf(-po));
    c_reg = sf * c_reg + si * tanhf(pg);
    const float hn = so * tanhf(c_reg);
    const u64 pk = ((u64)__float_as_uint(hn) << 32) | (u64)1u;
    u64* pp = &hg64[w * 16 + tid];     // s = 0
    st_sc0(pp, pk);    // fast visibility within this XCD's L2 (one wave, coalesced)
    EXCHS(pp, pk);     // durable publish at the device coherence point
  }
  __syncthreads();     // whh_s fully staged before the loop reads it

  // ---- LSTM loop: steps 1..15; hybrid sc0/system data-spin all-gather ----
  {
    const int r = tid >> 4;    // local gate row 0..63
    const int lj = tid & 15;   // slice lane

    for (int s = 1; s < NV; ++s) {
      if (tid < DD) {
        const u64* p = &hg64[(size_t)(s - 1) * DD + tid];
        u64 v = ld_sc0(p);                       // fast path: local-XCD L2
        while ((unsigned)v != (unsigned)s) {
          v = LOADS(p);                          // fallback: L3 (guarantees progress)
          if ((unsigned)v == (unsigned)s) break;
          v = ld_sc0(p);
        }
        h_s[tid] = __uint_as_float((unsigned)(v >> 32));
      }
      __syncthreads();

      float p = 0.f;
      const float4* wrow = (const float4*)&whh_s[r][0];
      const float4* hv4 = (const float4*)h_s;
#pragma unroll
      for (int q = 0; q < 8; ++q) {
        float4 wv = wrow[lj + 16 * q];
        float4 hv = hv4[lj + 16 * q];
        p += wv.x * hv.x + wv.y * hv.y + wv.z * hv.z + wv.w * hv.w;
      }
#pragma unroll
      for (int off = 8; off; off >>= 1) p += __shfl_down(p, off, 16);
      if (lj == 0) dot_s[r] = p;
      __syncthreads();

      if (tid < 16) {
        const float pi = gx_s[s][tid]      + dot_s[tid];
        const float pf = gx_s[s][16 + tid] + dot_s[16 + tid];
        const float pg = gx_s[s][32 + tid] + dot_s[32 + tid];
        const float po = gx_s[s][48 + tid] + dot_s[48 + tid];
        const float si = 1.f / (1.f + expf(-pi));
        const float sf = 1.f / (1.f + expf(-pf));
        const float so = 1.f / (1.f + expf(-po));
        c_reg = sf * c_reg + si * tanhf(pg);
        const float hn = so * tanhf(c_reg);
        const u64 pk = ((u64)__float_as_uint(hn) << 32) | (u64)(unsigned)(s + 1);
        u64* pp = &hg64[(size_t)s * DD + w * 16 + tid];
        st_sc0(pp, pk);    // fast visibility within this XCD's L2 (one wave, coalesced)
        EXCHS(pp, pk);     // durable publish at the device coherence point
      }
      // h_s/dot_s only rewritten after next step's barriers (two barriers away)
    }
  }

  // ---- classifier tail (worker 0 = blockIdx 0) ----
  if (wg == 0) {
    float* scratch = &whh_s[0][0];   // rows stride 516 (whh dead now)
    if (tid < DD) {
      u64 vv[NV];
#pragma unroll
      for (int n = 0; n < NV; ++n) vv[n] = LOADS(&hg64[(size_t)n * DD + tid]);
#pragma unroll
      for (int n = 0; n < NV; ++n) {
        u64 v = vv[n];
        while ((unsigned)v != (unsigned)(n + 1))
          v = LOADS(&hg64[(size_t)n * DD + tid]);   // backstop
        scratch[n * 516 + tid] = __uint_as_float((unsigned)(v >> 32));
      }
    }
    __syncthreads();
    if (tid < NV * NCLS) {
      const int n = tid >> 3, cl = tid & 7;
      const float4* hv = (const float4*)&scratch[n * 516];
      const float4* wv = (const float4*)(w_cls + (size_t)cl * DD);
      float a = b_cls[cl];
#pragma unroll 8
      for (int q = 0; q < DD / 4; ++q) {
        float4 x = hv[q], y = wv[q];
        a += x.x * y.x + x.y * y.y + x.z * y.z + x.w * y.w;
      }
      out[tid] = a;
    }
  }
}

extern "C" void kernel_launch(void* const* d_in, const int* in_sizes, int n_in,
                              void* d_out, int out_size, void* d_ws, size_t ws_size,
                              hipStream_t stream) {
  const float* base_out = (const float*)d_in[0];
  const float* dist     = (const float*)d_in[1];
  const float* w_a      = (const float*)d_in[2];
  const float* w_ih     = (const float*)d_in[3];
  const float* w_hh     = (const float*)d_in[4];
  const float* b_ih     = (const float*)d_in[5];
  const float* b_hh     = (const float*)d_in[6];
  const float* w_cls    = (const float*)d_in[7];
  const float* b_cls    = (const float*)d_in[8];
  float* out = (float*)d_out;

  float* ws = (float*)d_ws;
  float* part   = ws + PART_F;
  float* pooled = ws + POOLED_F;
  unsigned* tagGX = (unsigned*)(ws + TAGGX_F);
  u64* hg64 = (u64*)(ws + HGLOB_F);
  float* gxg = ws + GX_F;

  // Tags/values self-validate against the 0xAA re-poison (poison low word
  // 0xAAAAAAAA never equals a live tag 1..16 / 1).
  // Stream boundaries provide part -> k_pool and pooled -> k_rest visibility.
  k_gemm<<<dim3(3072), 64, 0, stream>>>(base_out, w_a, part);
  k_pool<<<dim3(256), 256, 0, stream>>>(dist, part, pooled);
  k_rest<<<dim3(256), 1024, 0, stream>>>(pooled, w_ih, w_hh, b_ih, b_hh,
                                         w_cls, b_cls, tagGX, gxg, hg64, out);
}